// Round 12
// baseline (575.836 us; speedup 1.0000x reference)
//
#include <hip/hip_runtime.h>
#include <hip/hip_bf16.h>
#include <math.h>

#define LEAKY 0.01f
#define B_    2048
#define F_    512
#define H_    64
#define K_    8
#define D_    128
#define ASR_  128
#define MM_   768
#define OUT_  256
#define PROJ_IN 66432          // 128+768+512*128
#define ZK    4992             // 896 + 512*8 (emb folded into proj_w)
#define NSPLIT 8               // gemm split-K (back to 8: 4 blocks/CU TLP)

// ---------------- workspace layout (bytes) ----------------
// A0   : [B_][896]     bf16   @ 0            3,670,016   (asr|mm pre-bf16)
// Pf   : [F_][B_][8]   bf16   @ 3,670,016   16,777,216   (probs, f-major)
// Wn   : [OUT_][ZK]    bf16   @ 20,447,232   2,555,904
// part : [8][B_][OUT_] fp32   @ 23,003,136  16,777,216
// total 39,780,352

typedef unsigned short u16;
typedef u16   u16x8 __attribute__((ext_vector_type(8)));
typedef short s16x8 __attribute__((ext_vector_type(8)));
typedef float f32x4 __attribute__((ext_vector_type(4)));

__device__ __forceinline__ u16 f2bf(float x) {   // RNE float->bf16 bits
  unsigned int u = __float_as_uint(x);
  u += 0x7fffu + ((u >> 16) & 1u);
  return (u16)(u >> 16);
}

// DPP quad reduction (VALU pipe; verified R8/R11).
// 0xB1 = quad_perm [1,0,3,2] (xor1), 0x4E = [2,3,0,1] (xor2).
__device__ __forceinline__ float quad_sum(float g) {
  int a = __builtin_amdgcn_update_dpp(0, __float_as_int(g), 0xB1, 0xF, 0xF, true);
  g += __int_as_float(a);
  int b = __builtin_amdgcn_update_dpp(0, __float_as_int(g), 0x4E, 0xF, 0xF, true);
  return g + __int_as_float(b);
}

// ---------------------------------------------------------------------------
// Fused producers, R0 dispatch order (wn_g first = longest-first).
// v8: wn_g = v7 wave-decoupled structure (verified R11: 42us, 0 conflicts,
// VGPR 32) with prefetch DEPTH 4 (va/vb/vc/vd named regs, 4-row unrolled
// groups; load reissued right after its ds_write -> issue->consume distance
// ~3 row-times ~550cyc, 4KB/wave in flight). Addressing identical to R11.
//   probs : R9/R11 verified (w2/b2/tau wave-uniform scalar loads, SMEM pipe)
//   a0    : asr|mm -> bf16                               [unchanged]
//   wn_top: bf16 copy of pw[:, :896]                     [unchanged]
#define PRODUCER_BLOCKS (512 + 1024 + 896 + 224)

__global__ __launch_bounds__(256) void producer_kernel(
    const float* __restrict__ stat, const float* __restrict__ w1,
    const float* __restrict__ b1v, const float* __restrict__ w2,
    const float* __restrict__ b2v, const float* __restrict__ tauv,
    const float* __restrict__ pw, const float* __restrict__ emb,
    const float* __restrict__ asr, const float* __restrict__ mm,
    u16* __restrict__ A0, u16* __restrict__ Pf, u16* __restrict__ Wn) {
  __shared__ __align__(16) char smem[15616];
  const int bid = blockIdx.x;
  const int t = threadIdx.x;

  if (bid < 512) {
    // ---------------- wn_g v8 (wave-decoupled, depth-4) ----------------
    // G[f,k,o] = sum_d emb[f,k,d] * pw[o, 896+f*128+d]
    const int f0 = (bid >> 3) * 8;                    // 64 f-groups of 8
    const int o0 = (bid & 7) * 32;                    // 8 o-chunks of 32
    const int w = t >> 6, lam = t & 63;
    const int fl = lam >> 5, k = (lam >> 2) & 7, dq = lam & 3;
    const int fbase = f0 + 2 * w;                     // this wave's 2 features
    float* sw = (float*)smem + w * 512;               // wave-private 2KB
    float* buf0 = sw;                                 // 256 floats each
    float* buf1 = sw + 256;
    const int wslot = lam ^ ((lam >> 3) & 7);         // swizzled 16B slot
    const int xr = fl * 4 + dq;                       // read-side XOR
    // emb fragment in registers: 32 floats (this lane's dq-quarter)
    float4 e[8];
    {
      const float* ep = emb + ((size_t)(fbase + fl) * 8 + k) * 128 + dq * 32;
      #pragma unroll
      for (int j = 0; j < 8; ++j) e[j] = *(const float4*)(ep + j * 4);
    }
    // linear coalesced source: lane lam loads logical floats [4lam..4lam+3]
    const float* gsrc = pw + 896 + (size_t)fbase * 128
                        + (size_t)o0 * PROJ_IN + lam * 4;
    u16* wdst = Wn + (size_t)o0 * ZK + 896 + (size_t)(fbase + fl) * 8 + k;
    const float* rd0 = buf0 + fl * 128 + dq * 32;
    const float* rd1 = buf1 + fl * 128 + dq * 32;
#define LDR(R) (*(const float4*)(gsrc + (size_t)(R) * PROJ_IN))
#define WNG_ROW(BUF, RD, VREG, R, NEXT)                                       \
    {                                                                         \
      *(float4*)((BUF) + wslot * 4) = VREG;          /* stage (vmcnt wait) */ \
      if ((NEXT) < 32) VREG = LDR(NEXT);             /* reissue ASAP */       \
      float g0 = 0.f, g1 = 0.f;                                               \
      _Pragma("unroll")                                                       \
      for (int j = 0; j < 8; ++j) {                                           \
        float4 p4 = *(const float4*)((RD) + 4 * (j ^ xr));                    \
        g0 = fmaf(e[j].x, p4.x, g0);                                          \
        g1 = fmaf(e[j].y, p4.y, g1);                                          \
        g0 = fmaf(e[j].z, p4.z, g0);                                          \
        g1 = fmaf(e[j].w, p4.w, g1);                                          \
      }                                                                       \
      float g = quad_sum(g0 + g1);                                            \
      if (dq == 0) wdst[(size_t)(R) * ZK] = f2bf(g);                          \
    }
    float4 va = LDR(0), vb = LDR(1), vc = LDR(2), vd = LDR(3);
    for (int gi = 0; gi < 8; ++gi) {                  // 4 rows per group
      const int r = 4 * gi;
      WNG_ROW(buf0, rd0, va, r,     r + 4);
      WNG_ROW(buf1, rd1, vb, r + 1, r + 5);
      WNG_ROW(buf0, rd0, vc, r + 2, r + 6);
      WNG_ROW(buf1, rd1, vd, r + 3, r + 7);
    }
#undef WNG_ROW
#undef LDR
  } else if (bid < 1536) {
    // ---------------- probs (R9/R11 verified): scalar w2/b2/tau ----------------
    const int pb = bid - 512;
    const int f0 = (pb & 127) * 4;
    const int b0 = (pb >> 7) * 256;
    float* s_w1s = (float*)(smem);                    // [4][64]   1024 B
    float* s_b1  = (float*)(smem + 1024);             // 1024 B
    float* s_x   = (float*)(smem + 2048);             // 256 rows x stride5 = 5120 B
    {
      int fl = t >> 6, h = t & 63;                    // 256 thr = 4 feat x 64 h
      const float* wf = w1 + (size_t)(f0 + fl) * 192;
      s_w1s[fl * 64 + h] = wf[h] + wf[64 + h] + wf[128 + h];  // x3 identical copies
      s_b1[fl * 64 + h] = b1v[(size_t)(f0 + fl) * 64 + h];
    }
    {
      // stat tile: one float4 per thread (row t, 4 consecutive features)
      float4 sv = *(const float4*)(stat + (size_t)(b0 + t) * F_ + f0);
      float* xr_ = s_x + t * 5;
      xr_[0] = (sv.x >= 0.f) ? sv.x : 0.f;            // NaN -> 0, neg -> 0
      xr_[1] = (sv.y >= 0.f) ? sv.y : 0.f;
      xr_[2] = (sv.z >= 0.f) ? sv.z : 0.f;
      xr_[3] = (sv.w >= 0.f) ? sv.w : 0.f;
    }
    __syncthreads();

    const int w = t >> 6;                             // wave-uniform feature
    const int wu = __builtin_amdgcn_readfirstlane(w); // force SGPR -> s_load path
    const int lane = t & 63;
    const float* w1p = s_w1s + w * 64;
    const float* b1p = s_b1 + w * 64;
    const float* w2u  = w2   + (size_t)(f0 + wu) * 512;   // uniform: SMEM pipe
    const float* b2u  = b2v  + (size_t)(f0 + wu) * 8;
    const float* tauu = tauv + (size_t)(f0 + wu) * 8;
    float x[4];
    #pragma unroll
    for (int p = 0; p < 4; ++p) x[p] = s_x[(lane + 64 * p) * 5 + w];
    float acc[4][8] = {{0.f}};
    #pragma unroll 4
    for (int i = 0; i < 64; ++i) {
      float wv = w1p[i], bv = b1p[i];                 // LDS broadcast (b32)
      float4 wa = *(const float4*)(w2u + i * 8);      // uniform scalar loads
      float4 wb = *(const float4*)(w2u + i * 8 + 4);
      #pragma unroll
      for (int p = 0; p < 4; ++p) {
        float h0 = fmaf(x[p], wv, bv);
        float h = fmaf(LEAKY, fminf(h0, 0.f), fmaxf(h0, 0.f));
        acc[p][0] = fmaf(h, wa.x, acc[p][0]);
        acc[p][1] = fmaf(h, wa.y, acc[p][1]);
        acc[p][2] = fmaf(h, wa.z, acc[p][2]);
        acc[p][3] = fmaf(h, wa.w, acc[p][3]);
        acc[p][4] = fmaf(h, wb.x, acc[p][4]);
        acc[p][5] = fmaf(h, wb.y, acc[p][5]);
        acc[p][6] = fmaf(h, wb.z, acc[p][6]);
        acc[p][7] = fmaf(h, wb.w, acc[p][7]);
      }
    }
    #pragma unroll
    for (int p = 0; p < 4; ++p) {
      float s[K_];
      float m = -1e30f;
      #pragma unroll
      for (int kk = 0; kk < K_; ++kk) {
        float v = acc[p][kk] + b2u[kk];
        v = (v >= 0.f) ? v : LEAKY * v;
        v *= tauu[kk];
        s[kk] = v;
        m = fmaxf(m, v);
      }
      float sum = 0.f;
      #pragma unroll
      for (int kk = 0; kk < K_; ++kk) { s[kk] = __expf(s[kk] - m); sum += s[kk]; }
      float inv = 1.f / sum;
      u16x8 hv;
      #pragma unroll
      for (int kk = 0; kk < K_; ++kk) hv[kk] = f2bf(s[kk] * inv);
      // Pf[f][b][8]: 64 consecutive rows/wave -> coalesced 16B stores
      *(u16x8*)(Pf + ((size_t)(f0 + w) * B_ + b0 + lane + 64 * p) * 8) = hv;
    }
  } else if (bid < 2432) {
    // ---------------- a0: A0[b][j] = bf16(asr|mm) ----------------
    const int item = bid - 1536;                      // 896 blocks x 2048 elems
    const int cidx = item * 256 + t;                  // chunk of 8; 112 chunks/row
    const int r = cidx / 112, c = cidx % 112;
    float4 v0, v1;
    if (c < 16) {
      const float* s = asr + (size_t)r * ASR_ + c * 8;
      v0 = *(const float4*)(s); v1 = *(const float4*)(s + 4);
    } else {
      const float* s = mm + (size_t)r * MM_ + (c - 16) * 8;
      v0 = *(const float4*)(s); v1 = *(const float4*)(s + 4);
    }
    u16x8 hv = {f2bf(v0.x), f2bf(v0.y), f2bf(v0.z), f2bf(v0.w),
                f2bf(v1.x), f2bf(v1.y), f2bf(v1.z), f2bf(v1.w)};
    *(u16x8*)(A0 + (size_t)r * 896 + c * 8) = hv;
  } else {
    // ---------------- wn_top: Wn[o][j] = bf16(pw[o][j]), j<896 ----------------
    const int item = bid - 2432;                      // 224 blocks x 1024 elems
    #pragma unroll
    for (int rr = 0; rr < 4; ++rr) {
      int idx = item * 1024 + rr * 256 + t;           // coalesced
      int o = idx / 896, j = idx % 896;
      Wn[(size_t)o * ZK + j] = f2bf(pw[(size_t)o * PROJ_IN + j]);
    }
  }
}

// ---------------------------------------------------------------------------
// MFMA GEMM, split-K=8: part[kz][b][o] = sum_{k slice} A[b][k]*Wn[o][k]
// BM=64 BN=64 BK=64; grid (32,4,8)=1024 blocks, 4/CU.
// v8: DISTANCE-2 register pipeline — tile i+2 loaded while tile i computes,
// two staging slots -> per-iter exposed load latency roughly halves.
#define SAS 72    // u16 row stride: 144 B
__global__ __launch_bounds__(256) void gemm_kernel(
    const u16* __restrict__ A0, const u16* __restrict__ Pf,
    const u16* __restrict__ Wn, float* __restrict__ part) {
  const int bm0 = blockIdx.x * 64;
  const int bn0 = blockIdx.y * 64;
  const int kz  = blockIdx.z;
  const int it0 = kz * 10;
  const int itn = (kz == 7) ? 8 : 10;                 // 7*10+8 = 78 iters of 64
  __shared__ u16 sA[64 * SAS];                        // 9216 B
  __shared__ u16 sB[64 * SAS];                        // 9216 B
  const int t = threadIdx.x;
  const int w = t >> 6, L = t & 63;
  const int l16 = L & 15, q8 = (L >> 4) * 8;
  const int wm = (w >> 1) * 32, wn = (w & 1) * 32;    // 2x2 wave grid
  const int row = t >> 2, lk = t & 3;                 // A0/Wn staging coords
  const int pp = t >> 5, pg = t & 31;                 // Pf staging coords
  f32x4 acc[2][2] = {{{0.f,0.f,0.f,0.f},{0.f,0.f,0.f,0.f}},
                     {{0.f,0.f,0.f,0.f},{0.f,0.f,0.f,0.f}}};
  u16x8 ra[2][2], rb[2][2];                           // [slot][piece]

#define LOAD_TILES(IT, S)                                                     \
  {                                                                           \
    const int k0_ = (IT) * 64;                                                \
    if (k0_ < 896) {                                                          \
      const u16* s_ = A0 + (size_t)(bm0 + row) * 896 + k0_ + lk * 8;          \
      ra[S][0] = *(const u16x8*)(s_);                                         \
      ra[S][1] = *(const u16x8*)(s_ + 32);                                    \
    } else {                                                                  \
      const int fb_ = (k0_ - 896) >> 3;                                       \
      const u16* s_ = Pf + ((size_t)(fb_ + pp) * B_ + bm0 + pg) * 8;          \
      ra[S][0] = *(const u16x8*)(s_);                                         \
      ra[S][1] = *(const u16x8*)(s_ + 256);   /* +32 rows */                  \
    }                                                                         \
    const u16* sb_ = Wn + (size_t)(bn0 + row) * ZK + k0_ + lk * 8;            \
    rb[S][0] = *(const u16x8*)(sb_);                                          \
    rb[S][1] = *(const u16x8*)(sb_ + 32);                                     \
  }

#define STORE_TILES(IT, S)                                                    \
  {                                                                           \
    if ((IT) * 64 < 896) {                                                    \
      *(u16x8*)&sA[row * SAS + lk * 8]      = ra[S][0];                       \
      *(u16x8*)&sA[row * SAS + lk * 8 + 32] = ra[S][1];                       \
    } else {                                                                  \
      *(u16x8*)&sA[pg * SAS + pp * 8]        = ra[S][0];                      \
      *(u16x8*)&sA[(pg + 32) * SAS + pp * 8] = ra[S][1];                      \
    }                                                                         \
    *(u16x8*)&sB[row * SAS + lk * 8]      = rb[S][0];                         \
    *(u16x8*)&sB[row * SAS + lk * 8 + 32] = rb[S][1];                         \
  }

  LOAD_TILES(it0, 0);
  if (itn > 1) LOAD_TILES(it0 + 1, 1);
  for (int it = it0; it < it0 + itn; ++it) {
    const int s = it & 1;
    __syncthreads();
    STORE_TILES(it, s);
    __syncthreads();
    if (it + 2 < it0 + itn) LOAD_TILES(it + 2, s);  // distance-2 prefetch
    #pragma unroll
    for (int ks = 0; ks < 2; ++ks) {
      s16x8 a0 = *(const s16x8*)&sA[(wm + l16) * SAS + ks * 32 + q8];
      s16x8 a1 = *(const s16x8*)&sA[(wm + 16 + l16) * SAS + ks * 32 + q8];
      s16x8 b0 = *(const s16x8*)&sB[(wn + l16) * SAS + ks * 32 + q8];
      s16x8 b1 = *(const s16x8*)&sB[(wn + 16 + l16) * SAS + ks * 32 + q8];
      acc[0][0] = __builtin_amdgcn_mfma_f32_16x16x32_bf16(a0, b0, acc[0][0], 0, 0, 0);
      acc[0][1] = __builtin_amdgcn_mfma_f32_16x16x32_bf16(a0, b1, acc[0][1], 0, 0, 0);
      acc[1][0] = __builtin_amdgcn_mfma_f32_16x16x32_bf16(a1, b0, acc[1][0], 0, 0, 0);
      acc[1][1] = __builtin_amdgcn_mfma_f32_16x16x32_bf16(a1, b1, acc[1][1], 0, 0, 0);
    }
  }
#undef LOAD_TILES
#undef STORE_TILES

  float* dst = part + (size_t)kz * B_ * OUT_;
  #pragma unroll
  for (int mf = 0; mf < 2; ++mf) {
    const int r0 = bm0 + wm + mf * 16 + (L >> 4) * 4;   // C/D: col=lane&15, row=quad*4+i
    #pragma unroll
    for (int nf = 0; nf < 2; ++nf) {
      const int col = bn0 + wn + nf * 16 + l16;
      #pragma unroll
      for (int i = 0; i < 4; ++i)
        dst[(size_t)(r0 + i) * OUT_ + col] = acc[mf][nf][i];
    }
  }
}

// ---------------------------------------------------------------------------
// combine: out = relu(sum_kz part[kz] + bias), float4 per thread
__global__ __launch_bounds__(256) void combine_kernel(
    const float* __restrict__ part, const float* __restrict__ pb,
    float* __restrict__ out) {
  const int idx4 = (blockIdx.x * 256 + threadIdx.x) * 4;
  const int o = idx4 & (OUT_ - 1);
  float4 bv = *(const float4*)(pb + o);
  float4 r = bv;
  #pragma unroll
  for (int kz = 0; kz < NSPLIT; ++kz) {
    float4 a = *(const float4*)(part + (size_t)kz * B_ * OUT_ + idx4);
    r.x += a.x; r.y += a.y; r.z += a.z; r.w += a.w;
  }
  r.x = r.x > 0.f ? r.x : 0.f;
  r.y = r.y > 0.f ? r.y : 0.f;
  r.z = r.z > 0.f ? r.z : 0.f;
  r.w = r.w > 0.f ? r.w : 0.f;
  *(float4*)(out + idx4) = r;
}

// ---------------------------------------------------------------------------
extern "C" void kernel_launch(void* const* d_in, const int* in_sizes, int n_in,
                              void* d_out, int out_size, void* d_ws, size_t ws_size,
                              hipStream_t stream) {
  (void)in_sizes; (void)n_in; (void)out_size; (void)ws_size;
  const float* stat = (const float*)d_in[0];
  const float* asr  = (const float*)d_in[1];
  const float* mm   = (const float*)d_in[2];
  const float* w1   = (const float*)d_in[3];
  const float* b1   = (const float*)d_in[4];
  const float* w2   = (const float*)d_in[5];
  const float* b2   = (const float*)d_in[6];
  const float* tau  = (const float*)d_in[7];
  const float* emb  = (const float*)d_in[8];
  const float* pw   = (const float*)d_in[9];
  const float* pb   = (const float*)d_in[10];
  float* out = (float*)d_out;
  char* ws = (char*)d_ws;
  u16*   A0   = (u16*)(ws);                 //  3,670,016 B
  u16*   Pf   = (u16*)(ws + 3670016);       // 16,777,216 B
  u16*   Wn   = (u16*)(ws + 20447232);      //  2,555,904 B
  float* part = (float*)(ws + 23003136);    // 16,777,216 B (NSPLIT=8)

  producer_kernel<<<PRODUCER_BLOCKS, 256, 0, stream>>>(
      stat, w1, b1, w2, b2, tau, pw, emb, asr, mm, A0, Pf, Wn);
  gemm_kernel<<<dim3(B_ / 64, OUT_ / 64, NSPLIT), 256, 0, stream>>>(
      A0, Pf, Wn, part);
  combine_kernel<<<B_ * OUT_ / 1024, 256, 0, stream>>>(part, pb, out);
}

// Round 14
// 154.834 us; speedup vs baseline: 3.7190x; 3.7190x over previous
//
#include <hip/hip_runtime.h>
#include <hip/hip_bf16.h>
#include <math.h>

#define LEAKY 0.01f
#define B_    2048
#define F_    512
#define H_    64
#define K_    8
#define D_    128
#define ASR_  128
#define MM_   768
#define OUT_  256
#define PROJ_IN 66432          // 128+768+512*128
#define ZK    4992             // 896 + 512*8 (emb folded into proj_w)
#define NSPLIT 8               // gemm split-K factor

// ---------------- workspace layout (bytes) ----------------
// A0   : [B_][896]     bf16   @ 0            3,670,016   (asr|mm pre-bf16)
// Pf   : [F_][B_][8]   bf16   @ 3,670,016   16,777,216   (probs, f-major)
// Wn   : [OUT_][ZK]    bf16   @ 20,447,232   2,555,904
// part : [8][B_][OUT_] fp32   @ 23,003,136  16,777,216
// total 39,780,352

typedef unsigned short u16;
typedef u16   u16x8 __attribute__((ext_vector_type(8)));
typedef short s16x8 __attribute__((ext_vector_type(8)));
typedef float f32x4 __attribute__((ext_vector_type(4)));

__device__ __forceinline__ u16 f2bf(float x) {   // RNE float->bf16 bits
  unsigned int u = __float_as_uint(x);
  u += 0x7fffu + ((u >> 16) & 1u);
  return (u16)(u >> 16);
}

// DPP quad reduction (VALU pipe; verified R8/R11/R12).
// 0xB1 = quad_perm [1,0,3,2] (xor1), 0x4E = [2,3,0,1] (xor2).
__device__ __forceinline__ float quad_sum(float g) {
  int a = __builtin_amdgcn_update_dpp(0, __float_as_int(g), 0xB1, 0xF, 0xF, true);
  g += __int_as_float(a);
  int b = __builtin_amdgcn_update_dpp(0, __float_as_int(g), 0x4E, 0xF, 0xF, true);
  return g + __int_as_float(b);
}

// ---------------------------------------------------------------------------
// Fused producers, R0 dispatch order (wn_g first = longest-first).
// producer v8 (correctness-verified R12): wn_g wave-decoupled + DEPTH-4
// prefetch (named va/vb/vc/vd, 4-row unrolled groups; load reissued right
// after its ds_write). probs: scalar w2/b2/tau (SMEM pipe, verified R9/R11).
// NOTE (R12 lesson, guide rule #20): NEVER index register tile arrays with a
// runtime value — it spills to scratch (gemm went 26->455us).
#define PRODUCER_BLOCKS (512 + 1024 + 896 + 224)

__global__ __launch_bounds__(256) void producer_kernel(
    const float* __restrict__ stat, const float* __restrict__ w1,
    const float* __restrict__ b1v, const float* __restrict__ w2,
    const float* __restrict__ b2v, const float* __restrict__ tauv,
    const float* __restrict__ pw, const float* __restrict__ emb,
    const float* __restrict__ asr, const float* __restrict__ mm,
    u16* __restrict__ A0, u16* __restrict__ Pf, u16* __restrict__ Wn) {
  __shared__ __align__(16) char smem[15616];
  const int bid = blockIdx.x;
  const int t = threadIdx.x;

  if (bid < 512) {
    // ---------------- wn_g v8 (wave-decoupled, depth-4) ----------------
    // G[f,k,o] = sum_d emb[f,k,d] * pw[o, 896+f*128+d]
    const int f0 = (bid >> 3) * 8;                    // 64 f-groups of 8
    const int o0 = (bid & 7) * 32;                    // 8 o-chunks of 32
    const int w = t >> 6, lam = t & 63;
    const int fl = lam >> 5, k = (lam >> 2) & 7, dq = lam & 3;
    const int fbase = f0 + 2 * w;                     // this wave's 2 features
    float* sw = (float*)smem + w * 512;               // wave-private 2KB
    float* buf0 = sw;                                 // 256 floats each
    float* buf1 = sw + 256;
    const int wslot = lam ^ ((lam >> 3) & 7);         // swizzled 16B slot
    const int xr = fl * 4 + dq;                       // read-side XOR
    // emb fragment in registers: 32 floats (this lane's dq-quarter)
    float4 e[8];
    {
      const float* ep = emb + ((size_t)(fbase + fl) * 8 + k) * 128 + dq * 32;
      #pragma unroll
      for (int j = 0; j < 8; ++j) e[j] = *(const float4*)(ep + j * 4);
    }
    // linear coalesced source: lane lam loads logical floats [4lam..4lam+3]
    const float* gsrc = pw + 896 + (size_t)fbase * 128
                        + (size_t)o0 * PROJ_IN + lam * 4;
    u16* wdst = Wn + (size_t)o0 * ZK + 896 + (size_t)(fbase + fl) * 8 + k;
    const float* rd0 = buf0 + fl * 128 + dq * 32;
    const float* rd1 = buf1 + fl * 128 + dq * 32;
#define LDR(R) (*(const float4*)(gsrc + (size_t)(R) * PROJ_IN))
#define WNG_ROW(BUF, RD, VREG, R, NEXT)                                       \
    {                                                                         \
      *(float4*)((BUF) + wslot * 4) = VREG;          /* stage (vmcnt wait) */ \
      if ((NEXT) < 32) VREG = LDR(NEXT);             /* reissue ASAP */       \
      float g0 = 0.f, g1 = 0.f;                                               \
      _Pragma("unroll")                                                       \
      for (int j = 0; j < 8; ++j) {                                           \
        float4 p4 = *(const float4*)((RD) + 4 * (j ^ xr));                    \
        g0 = fmaf(e[j].x, p4.x, g0);                                          \
        g1 = fmaf(e[j].y, p4.y, g1);                                          \
        g0 = fmaf(e[j].z, p4.z, g0);                                          \
        g1 = fmaf(e[j].w, p4.w, g1);                                          \
      }                                                                       \
      float g = quad_sum(g0 + g1);                                            \
      if (dq == 0) wdst[(size_t)(R) * ZK] = f2bf(g);                          \
    }
    float4 va = LDR(0), vb = LDR(1), vc = LDR(2), vd = LDR(3);
    for (int gi = 0; gi < 8; ++gi) {                  // 4 rows per group
      const int r = 4 * gi;
      WNG_ROW(buf0, rd0, va, r,     r + 4);
      WNG_ROW(buf1, rd1, vb, r + 1, r + 5);
      WNG_ROW(buf0, rd0, vc, r + 2, r + 6);
      WNG_ROW(buf1, rd1, vd, r + 3, r + 7);
    }
#undef WNG_ROW
#undef LDR
  } else if (bid < 1536) {
    // ---------------- probs (R9/R11 verified): scalar w2/b2/tau ----------------
    const int pb = bid - 512;
    const int f0 = (pb & 127) * 4;
    const int b0 = (pb >> 7) * 256;
    float* s_w1s = (float*)(smem);                    // [4][64]   1024 B
    float* s_b1  = (float*)(smem + 1024);             // 1024 B
    float* s_x   = (float*)(smem + 2048);             // 256 rows x stride5 = 5120 B
    {
      int fl = t >> 6, h = t & 63;                    // 256 thr = 4 feat x 64 h
      const float* wf = w1 + (size_t)(f0 + fl) * 192;
      s_w1s[fl * 64 + h] = wf[h] + wf[64 + h] + wf[128 + h];  // x3 identical copies
      s_b1[fl * 64 + h] = b1v[(size_t)(f0 + fl) * 64 + h];
    }
    {
      // stat tile: one float4 per thread (row t, 4 consecutive features)
      float4 sv = *(const float4*)(stat + (size_t)(b0 + t) * F_ + f0);
      float* xr_ = s_x + t * 5;
      xr_[0] = (sv.x >= 0.f) ? sv.x : 0.f;            // NaN -> 0, neg -> 0
      xr_[1] = (sv.y >= 0.f) ? sv.y : 0.f;
      xr_[2] = (sv.z >= 0.f) ? sv.z : 0.f;
      xr_[3] = (sv.w >= 0.f) ? sv.w : 0.f;
    }
    __syncthreads();

    const int w = t >> 6;                             // wave-uniform feature
    const int wu = __builtin_amdgcn_readfirstlane(w); // force SGPR -> s_load path
    const int lane = t & 63;
    const float* w1p = s_w1s + w * 64;
    const float* b1p = s_b1 + w * 64;
    const float* w2u  = w2   + (size_t)(f0 + wu) * 512;   // uniform: SMEM pipe
    const float* b2u  = b2v  + (size_t)(f0 + wu) * 8;
    const float* tauu = tauv + (size_t)(f0 + wu) * 8;
    float x[4];
    #pragma unroll
    for (int p = 0; p < 4; ++p) x[p] = s_x[(lane + 64 * p) * 5 + w];
    float acc[4][8] = {{0.f}};
    #pragma unroll 4
    for (int i = 0; i < 64; ++i) {
      float wv = w1p[i], bv = b1p[i];                 // LDS broadcast (b32)
      float4 wa = *(const float4*)(w2u + i * 8);      // uniform scalar loads
      float4 wb = *(const float4*)(w2u + i * 8 + 4);
      #pragma unroll
      for (int p = 0; p < 4; ++p) {
        float h0 = fmaf(x[p], wv, bv);
        float h = fmaf(LEAKY, fminf(h0, 0.f), fmaxf(h0, 0.f));
        acc[p][0] = fmaf(h, wa.x, acc[p][0]);
        acc[p][1] = fmaf(h, wa.y, acc[p][1]);
        acc[p][2] = fmaf(h, wa.z, acc[p][2]);
        acc[p][3] = fmaf(h, wa.w, acc[p][3]);
        acc[p][4] = fmaf(h, wb.x, acc[p][4]);
        acc[p][5] = fmaf(h, wb.y, acc[p][5]);
        acc[p][6] = fmaf(h, wb.z, acc[p][6]);
        acc[p][7] = fmaf(h, wb.w, acc[p][7]);
      }
    }
    #pragma unroll
    for (int p = 0; p < 4; ++p) {
      float s[K_];
      float m = -1e30f;
      #pragma unroll
      for (int kk = 0; kk < K_; ++kk) {
        float v = acc[p][kk] + b2u[kk];
        v = (v >= 0.f) ? v : LEAKY * v;
        v *= tauu[kk];
        s[kk] = v;
        m = fmaxf(m, v);
      }
      float sum = 0.f;
      #pragma unroll
      for (int kk = 0; kk < K_; ++kk) { s[kk] = __expf(s[kk] - m); sum += s[kk]; }
      float inv = 1.f / sum;
      u16x8 hv;
      #pragma unroll
      for (int kk = 0; kk < K_; ++kk) hv[kk] = f2bf(s[kk] * inv);
      // Pf[f][b][8]: 64 consecutive rows/wave -> coalesced 16B stores
      *(u16x8*)(Pf + ((size_t)(f0 + w) * B_ + b0 + lane + 64 * p) * 8) = hv;
    }
  } else if (bid < 2432) {
    // ---------------- a0: A0[b][j] = bf16(asr|mm) ----------------
    const int item = bid - 1536;                      // 896 blocks x 2048 elems
    const int cidx = item * 256 + t;                  // chunk of 8; 112 chunks/row
    const int r = cidx / 112, c = cidx % 112;
    float4 v0, v1;
    if (c < 16) {
      const float* s = asr + (size_t)r * ASR_ + c * 8;
      v0 = *(const float4*)(s); v1 = *(const float4*)(s + 4);
    } else {
      const float* s = mm + (size_t)r * MM_ + (c - 16) * 8;
      v0 = *(const float4*)(s); v1 = *(const float4*)(s + 4);
    }
    u16x8 hv = {f2bf(v0.x), f2bf(v0.y), f2bf(v0.z), f2bf(v0.w),
                f2bf(v1.x), f2bf(v1.y), f2bf(v1.z), f2bf(v1.w)};
    *(u16x8*)(A0 + (size_t)r * 896 + c * 8) = hv;
  } else {
    // ---------------- wn_top: Wn[o][j] = bf16(pw[o][j]), j<896 ----------------
    const int item = bid - 2432;                      // 224 blocks x 1024 elems
    #pragma unroll
    for (int rr = 0; rr < 4; ++rr) {
      int idx = item * 1024 + rr * 256 + t;           // coalesced
      int o = idx / 896, j = idx % 896;
      Wn[(size_t)o * ZK + j] = f2bf(pw[(size_t)o * PROJ_IN + j]);
    }
  }
}

// ---------------------------------------------------------------------------
// MFMA GEMM, split-K=8 — EXACT R0/R9/R11 body (verified ~25us across 8 runs).
// Distance-1 staging, compile-time slot indices only (R12 rule-#20 lesson).
#define SAS 72    // u16 row stride: 144 B
__global__ __launch_bounds__(256) void gemm_kernel(
    const u16* __restrict__ A0, const u16* __restrict__ Pf,
    const u16* __restrict__ Wn, float* __restrict__ part) {
  const int bm0 = blockIdx.x * 64;
  const int bn0 = blockIdx.y * 64;
  const int kz  = blockIdx.z;
  const int it0 = kz * 10;
  const int itn = (kz == 7) ? 8 : 10;                 // 7*10+8 = 78 iters of 64
  __shared__ u16 sA[64 * SAS];                        // 9216 B
  __shared__ u16 sB[64 * SAS];                        // 9216 B
  const int t = threadIdx.x;
  const int w = t >> 6, L = t & 63;
  const int l16 = L & 15, q8 = (L >> 4) * 8;
  const int wm = (w >> 1) * 32, wn = (w & 1) * 32;    // 2x2 wave grid
  const int row = t >> 2, lk = t & 3;                 // A0/Wn staging coords
  const int pp = t >> 5, pg = t & 31;                 // Pf staging coords
  f32x4 acc[2][2] = {{{0.f,0.f,0.f,0.f},{0.f,0.f,0.f,0.f}},
                     {{0.f,0.f,0.f,0.f},{0.f,0.f,0.f,0.f}}};
  u16x8 ra[2], rb[2];

#define LOAD_TILES(IT)                                                        \
  {                                                                           \
    const int k0_ = (IT) * 64;                                                \
    if (k0_ < 896) {                                                          \
      const u16* s_ = A0 + (size_t)(bm0 + row) * 896 + k0_ + lk * 8;          \
      ra[0] = *(const u16x8*)(s_);                                            \
      ra[1] = *(const u16x8*)(s_ + 32);                                       \
    } else {                                                                  \
      const int fb_ = (k0_ - 896) >> 3;                                       \
      const u16* s_ = Pf + ((size_t)(fb_ + pp) * B_ + bm0 + pg) * 8;          \
      ra[0] = *(const u16x8*)(s_);                                            \
      ra[1] = *(const u16x8*)(s_ + 256);   /* +32 rows */                     \
    }                                                                         \
    const u16* sb_ = Wn + (size_t)(bn0 + row) * ZK + k0_ + lk * 8;            \
    rb[0] = *(const u16x8*)(sb_);                                             \
    rb[1] = *(const u16x8*)(sb_ + 32);                                        \
  }

#define STORE_TILES(IT)                                                       \
  {                                                                           \
    if ((IT) * 64 < 896) {                                                    \
      *(u16x8*)&sA[row * SAS + lk * 8]      = ra[0];                          \
      *(u16x8*)&sA[row * SAS + lk * 8 + 32] = ra[1];                          \
    } else {                                                                  \
      *(u16x8*)&sA[pg * SAS + pp * 8]        = ra[0];                         \
      *(u16x8*)&sA[(pg + 32) * SAS + pp * 8] = ra[1];                         \
    }                                                                         \
    *(u16x8*)&sB[row * SAS + lk * 8]      = rb[0];                            \
    *(u16x8*)&sB[row * SAS + lk * 8 + 32] = rb[1];                            \
  }

  LOAD_TILES(it0);
  for (int it = it0; it < it0 + itn; ++it) {
    __syncthreads();
    STORE_TILES(it);
    __syncthreads();
    if (it + 1 < it0 + itn) LOAD_TILES(it + 1);   // overlap next load with MFMA
    #pragma unroll
    for (int ks = 0; ks < 2; ++ks) {
      s16x8 a0 = *(const s16x8*)&sA[(wm + l16) * SAS + ks * 32 + q8];
      s16x8 a1 = *(const s16x8*)&sA[(wm + 16 + l16) * SAS + ks * 32 + q8];
      s16x8 b0 = *(const s16x8*)&sB[(wn + l16) * SAS + ks * 32 + q8];
      s16x8 b1 = *(const s16x8*)&sB[(wn + 16 + l16) * SAS + ks * 32 + q8];
      acc[0][0] = __builtin_amdgcn_mfma_f32_16x16x32_bf16(a0, b0, acc[0][0], 0, 0, 0);
      acc[0][1] = __builtin_amdgcn_mfma_f32_16x16x32_bf16(a0, b1, acc[0][1], 0, 0, 0);
      acc[1][0] = __builtin_amdgcn_mfma_f32_16x16x32_bf16(a1, b0, acc[1][0], 0, 0, 0);
      acc[1][1] = __builtin_amdgcn_mfma_f32_16x16x32_bf16(a1, b1, acc[1][1], 0, 0, 0);
    }
  }
#undef LOAD_TILES
#undef STORE_TILES

  float* dst = part + (size_t)kz * B_ * OUT_;
  #pragma unroll
  for (int mf = 0; mf < 2; ++mf) {
    const int r0 = bm0 + wm + mf * 16 + (L >> 4) * 4;   // C/D: col=lane&15, row=quad*4+i
    #pragma unroll
    for (int nf = 0; nf < 2; ++nf) {
      const int col = bn0 + wn + nf * 16 + l16;
      #pragma unroll
      for (int i = 0; i < 4; ++i)
        dst[(size_t)(r0 + i) * OUT_ + col] = acc[mf][nf][i];
    }
  }
}

// ---------------------------------------------------------------------------
// combine: out = relu(sum_kz part[kz] + bias), float4 per thread
__global__ __launch_bounds__(256) void combine_kernel(
    const float* __restrict__ part, const float* __restrict__ pb,
    float* __restrict__ out) {
  const int idx4 = (blockIdx.x * 256 + threadIdx.x) * 4;
  const int o = idx4 & (OUT_ - 1);
  float4 bv = *(const float4*)(pb + o);
  float4 r = bv;
  #pragma unroll
  for (int kz = 0; kz < NSPLIT; ++kz) {
    float4 a = *(const float4*)(part + (size_t)kz * B_ * OUT_ + idx4);
    r.x += a.x; r.y += a.y; r.z += a.z; r.w += a.w;
  }
  r.x = r.x > 0.f ? r.x : 0.f;
  r.y = r.y > 0.f ? r.y : 0.f;
  r.z = r.z > 0.f ? r.z : 0.f;
  r.w = r.w > 0.f ? r.w : 0.f;
  *(float4*)(out + idx4) = r;
}

// ---------------------------------------------------------------------------
extern "C" void kernel_launch(void* const* d_in, const int* in_sizes, int n_in,
                              void* d_out, int out_size, void* d_ws, size_t ws_size,
                              hipStream_t stream) {
  (void)in_sizes; (void)n_in; (void)out_size; (void)ws_size;
  const float* stat = (const float*)d_in[0];
  const float* asr  = (const float*)d_in[1];
  const float* mm   = (const float*)d_in[2];
  const float* w1   = (const float*)d_in[3];
  const float* b1   = (const float*)d_in[4];
  const float* w2   = (const float*)d_in[5];
  const float* b2   = (const float*)d_in[6];
  const float* tau  = (const float*)d_in[7];
  const float* emb  = (const float*)d_in[8];
  const float* pw   = (const float*)d_in[9];
  const float* pb   = (const float*)d_in[10];
  float* out = (float*)d_out;
  char* ws = (char*)d_ws;
  u16*   A0   = (u16*)(ws);                 //  3,670,016 B
  u16*   Pf   = (u16*)(ws + 3670016);       // 16,777,216 B
  u16*   Wn   = (u16*)(ws + 20447232);      //  2,555,904 B
  float* part = (float*)(ws + 23003136);    // 16,777,216 B (NSPLIT=8)

  producer_kernel<<<PRODUCER_BLOCKS, 256, 0, stream>>>(
      stat, w1, b1, w2, b2, tau, pw, emb, asr, mm, A0, Pf, Wn);
  gemm_kernel<<<dim3(B_ / 64, OUT_ / 64, NSPLIT), 256, 0, stream>>>(
      A0, Pf, Wn, part);
  combine_kernel<<<B_ * OUT_ / 1024, 256, 0, stream>>>(part, pb, out);
}

// Round 15
// 154.604 us; speedup vs baseline: 3.7246x; 1.0015x over previous
//
#include <hip/hip_runtime.h>
#include <hip/hip_bf16.h>
#include <math.h>

#define LEAKY 0.01f
#define B_    2048
#define F_    512
#define H_    64
#define K_    8
#define D_    128
#define ASR_  128
#define MM_   768
#define OUT_  256
#define PROJ_IN 66432          // 128+768+512*128
#define ZK    4992             // 896 + 512*8 (emb folded into proj_w)
#define NSPLIT 8               // gemm split-K factor

// ---------------- workspace layout (bytes) ----------------
// A0   : [B_][896]     bf16   @ 0            3,670,016   (asr|mm pre-bf16)
// Pf   : [F_][B_][8]   bf16   @ 3,670,016   16,777,216   (probs, f-major)
// Wn   : [OUT_][ZK]    bf16   @ 20,447,232   2,555,904
// part : [8][B_][OUT_] fp32   @ 23,003,136  16,777,216
// total 39,780,352

typedef unsigned short u16;
typedef u16   u16x8 __attribute__((ext_vector_type(8)));
typedef short s16x8 __attribute__((ext_vector_type(8)));
typedef float f32x4 __attribute__((ext_vector_type(4)));

__device__ __forceinline__ u16 f2bf(float x) {   // RNE float->bf16 bits
  unsigned int u = __float_as_uint(x);
  u += 0x7fffu + ((u >> 16) & 1u);
  return (u16)(u >> 16);
}

// DPP quad reduction (VALU pipe; verified R8/R11/R12/R14).
// 0xB1 = quad_perm [1,0,3,2] (xor1), 0x4E = [2,3,0,1] (xor2).
__device__ __forceinline__ float quad_sum(float g) {
  int a = __builtin_amdgcn_update_dpp(0, __float_as_int(g), 0xB1, 0xF, 0xF, true);
  g += __int_as_float(a);
  int b = __builtin_amdgcn_update_dpp(0, __float_as_int(g), 0x4E, 0xF, 0xF, true);
  return g + __int_as_float(b);
}

// ---------------------------------------------------------------------------
// Fused producers — byte-identical to R14 best (154.8us; producer <41.4us):
// wn_g v8 (wave-decoupled, depth-4 named-reg prefetch), probs scalar-load,
// a0, wn_top. FROZEN this round to isolate the gemm change.
#define PRODUCER_BLOCKS (512 + 1024 + 896 + 224)

__global__ __launch_bounds__(256) void producer_kernel(
    const float* __restrict__ stat, const float* __restrict__ w1,
    const float* __restrict__ b1v, const float* __restrict__ w2,
    const float* __restrict__ b2v, const float* __restrict__ tauv,
    const float* __restrict__ pw, const float* __restrict__ emb,
    const float* __restrict__ asr, const float* __restrict__ mm,
    u16* __restrict__ A0, u16* __restrict__ Pf, u16* __restrict__ Wn) {
  __shared__ __align__(16) char smem[15616];
  const int bid = blockIdx.x;
  const int t = threadIdx.x;

  if (bid < 512) {
    // ---------------- wn_g v8 (wave-decoupled, depth-4) ----------------
    // G[f,k,o] = sum_d emb[f,k,d] * pw[o, 896+f*128+d]
    const int f0 = (bid >> 3) * 8;                    // 64 f-groups of 8
    const int o0 = (bid & 7) * 32;                    // 8 o-chunks of 32
    const int w = t >> 6, lam = t & 63;
    const int fl = lam >> 5, k = (lam >> 2) & 7, dq = lam & 3;
    const int fbase = f0 + 2 * w;                     // this wave's 2 features
    float* sw = (float*)smem + w * 512;               // wave-private 2KB
    float* buf0 = sw;                                 // 256 floats each
    float* buf1 = sw + 256;
    const int wslot = lam ^ ((lam >> 3) & 7);         // swizzled 16B slot
    const int xr = fl * 4 + dq;                       // read-side XOR
    // emb fragment in registers: 32 floats (this lane's dq-quarter)
    float4 e[8];
    {
      const float* ep = emb + ((size_t)(fbase + fl) * 8 + k) * 128 + dq * 32;
      #pragma unroll
      for (int j = 0; j < 8; ++j) e[j] = *(const float4*)(ep + j * 4);
    }
    // linear coalesced source: lane lam loads logical floats [4lam..4lam+3]
    const float* gsrc = pw + 896 + (size_t)fbase * 128
                        + (size_t)o0 * PROJ_IN + lam * 4;
    u16* wdst = Wn + (size_t)o0 * ZK + 896 + (size_t)(fbase + fl) * 8 + k;
    const float* rd0 = buf0 + fl * 128 + dq * 32;
    const float* rd1 = buf1 + fl * 128 + dq * 32;
#define LDR(R) (*(const float4*)(gsrc + (size_t)(R) * PROJ_IN))
#define WNG_ROW(BUF, RD, VREG, R, NEXT)                                       \
    {                                                                         \
      *(float4*)((BUF) + wslot * 4) = VREG;          /* stage (vmcnt wait) */ \
      if ((NEXT) < 32) VREG = LDR(NEXT);             /* reissue ASAP */       \
      float g0 = 0.f, g1 = 0.f;                                               \
      _Pragma("unroll")                                                       \
      for (int j = 0; j < 8; ++j) {                                           \
        float4 p4 = *(const float4*)((RD) + 4 * (j ^ xr));                    \
        g0 = fmaf(e[j].x, p4.x, g0);                                          \
        g1 = fmaf(e[j].y, p4.y, g1);                                          \
        g0 = fmaf(e[j].z, p4.z, g0);                                          \
        g1 = fmaf(e[j].w, p4.w, g1);                                          \
      }                                                                       \
      float g = quad_sum(g0 + g1);                                            \
      if (dq == 0) wdst[(size_t)(R) * ZK] = f2bf(g);                          \
    }
    float4 va = LDR(0), vb = LDR(1), vc = LDR(2), vd = LDR(3);
    for (int gi = 0; gi < 8; ++gi) {                  // 4 rows per group
      const int r = 4 * gi;
      WNG_ROW(buf0, rd0, va, r,     r + 4);
      WNG_ROW(buf1, rd1, vb, r + 1, r + 5);
      WNG_ROW(buf0, rd0, vc, r + 2, r + 6);
      WNG_ROW(buf1, rd1, vd, r + 3, r + 7);
    }
#undef WNG_ROW
#undef LDR
  } else if (bid < 1536) {
    // ---------------- probs (R9/R11/R14 verified): scalar w2/b2/tau ----------------
    const int pb = bid - 512;
    const int f0 = (pb & 127) * 4;
    const int b0 = (pb >> 7) * 256;
    float* s_w1s = (float*)(smem);                    // [4][64]   1024 B
    float* s_b1  = (float*)(smem + 1024);             // 1024 B
    float* s_x   = (float*)(smem + 2048);             // 256 rows x stride5 = 5120 B
    {
      int fl = t >> 6, h = t & 63;                    // 256 thr = 4 feat x 64 h
      const float* wf = w1 + (size_t)(f0 + fl) * 192;
      s_w1s[fl * 64 + h] = wf[h] + wf[64 + h] + wf[128 + h];  // x3 identical copies
      s_b1[fl * 64 + h] = b1v[(size_t)(f0 + fl) * 64 + h];
    }
    {
      // stat tile: one float4 per thread (row t, 4 consecutive features)
      float4 sv = *(const float4*)(stat + (size_t)(b0 + t) * F_ + f0);
      float* xr_ = s_x + t * 5;
      xr_[0] = (sv.x >= 0.f) ? sv.x : 0.f;            // NaN -> 0, neg -> 0
      xr_[1] = (sv.y >= 0.f) ? sv.y : 0.f;
      xr_[2] = (sv.z >= 0.f) ? sv.z : 0.f;
      xr_[3] = (sv.w >= 0.f) ? sv.w : 0.f;
    }
    __syncthreads();

    const int w = t >> 6;                             // wave-uniform feature
    const int wu = __builtin_amdgcn_readfirstlane(w); // force SGPR -> s_load path
    const int lane = t & 63;
    const float* w1p = s_w1s + w * 64;
    const float* b1p = s_b1 + w * 64;
    const float* w2u  = w2   + (size_t)(f0 + wu) * 512;   // uniform: SMEM pipe
    const float* b2u  = b2v  + (size_t)(f0 + wu) * 8;
    const float* tauu = tauv + (size_t)(f0 + wu) * 8;
    float x[4];
    #pragma unroll
    for (int p = 0; p < 4; ++p) x[p] = s_x[(lane + 64 * p) * 5 + w];
    float acc[4][8] = {{0.f}};
    #pragma unroll 4
    for (int i = 0; i < 64; ++i) {
      float wv = w1p[i], bv = b1p[i];                 // LDS broadcast (b32)
      float4 wa = *(const float4*)(w2u + i * 8);      // uniform scalar loads
      float4 wb = *(const float4*)(w2u + i * 8 + 4);
      #pragma unroll
      for (int p = 0; p < 4; ++p) {
        float h0 = fmaf(x[p], wv, bv);
        float h = fmaf(LEAKY, fminf(h0, 0.f), fmaxf(h0, 0.f));
        acc[p][0] = fmaf(h, wa.x, acc[p][0]);
        acc[p][1] = fmaf(h, wa.y, acc[p][1]);
        acc[p][2] = fmaf(h, wa.z, acc[p][2]);
        acc[p][3] = fmaf(h, wa.w, acc[p][3]);
        acc[p][4] = fmaf(h, wb.x, acc[p][4]);
        acc[p][5] = fmaf(h, wb.y, acc[p][5]);
        acc[p][6] = fmaf(h, wb.z, acc[p][6]);
        acc[p][7] = fmaf(h, wb.w, acc[p][7]);
      }
    }
    #pragma unroll
    for (int p = 0; p < 4; ++p) {
      float s[K_];
      float m = -1e30f;
      #pragma unroll
      for (int kk = 0; kk < K_; ++kk) {
        float v = acc[p][kk] + b2u[kk];
        v = (v >= 0.f) ? v : LEAKY * v;
        v *= tauu[kk];
        s[kk] = v;
        m = fmaxf(m, v);
      }
      float sum = 0.f;
      #pragma unroll
      for (int kk = 0; kk < K_; ++kk) { s[kk] = __expf(s[kk] - m); sum += s[kk]; }
      float inv = 1.f / sum;
      u16x8 hv;
      #pragma unroll
      for (int kk = 0; kk < K_; ++kk) hv[kk] = f2bf(s[kk] * inv);
      // Pf[f][b][8]: 64 consecutive rows/wave -> coalesced 16B stores
      *(u16x8*)(Pf + ((size_t)(f0 + w) * B_ + b0 + lane + 64 * p) * 8) = hv;
    }
  } else if (bid < 2432) {
    // ---------------- a0: A0[b][j] = bf16(asr|mm) ----------------
    const int item = bid - 1536;                      // 896 blocks x 2048 elems
    const int cidx = item * 256 + t;                  // chunk of 8; 112 chunks/row
    const int r = cidx / 112, c = cidx % 112;
    float4 v0, v1;
    if (c < 16) {
      const float* s = asr + (size_t)r * ASR_ + c * 8;
      v0 = *(const float4*)(s); v1 = *(const float4*)(s + 4);
    } else {
      const float* s = mm + (size_t)r * MM_ + (c - 16) * 8;
      v0 = *(const float4*)(s); v1 = *(const float4*)(s + 4);
    }
    u16x8 hv = {f2bf(v0.x), f2bf(v0.y), f2bf(v0.z), f2bf(v0.w),
                f2bf(v1.x), f2bf(v1.y), f2bf(v1.z), f2bf(v1.w)};
    *(u16x8*)(A0 + (size_t)r * 896 + c * 8) = hv;
  } else {
    // ---------------- wn_top: Wn[o][j] = bf16(pw[o][j]), j<896 ----------------
    const int item = bid - 2432;                      // 224 blocks x 1024 elems
    #pragma unroll
    for (int rr = 0; rr < 4; ++rr) {
      int idx = item * 1024 + rr * 256 + t;           // coalesced
      int o = idx / 896, j = idx % 896;
      Wn[(size_t)o * ZK + j] = f2bf(pw[(size_t)o * PROJ_IN + j]);
    }
  }
}

// ---------------------------------------------------------------------------
// MFMA GEMM, split-K=8 — v2: DISTANCE-2 register pipeline via unroll-by-2
// with NAMED slot sets (raA/rbA, raB/rbB) — all indices compile-time
// (R12 rule-#20 lesson: runtime-indexed reg arrays spill to scratch).
// itn in {8,10} is always even, so the pair loop is exact.
#define SAS 72    // u16 row stride: 144 B
__global__ __launch_bounds__(256) void gemm_kernel(
    const u16* __restrict__ A0, const u16* __restrict__ Pf,
    const u16* __restrict__ Wn, float* __restrict__ part) {
  const int bm0 = blockIdx.x * 64;
  const int bn0 = blockIdx.y * 64;
  const int kz  = blockIdx.z;
  const int it0 = kz * 10;
  const int itn = (kz == 7) ? 8 : 10;                 // 7*10+8 = 78 iters of 64
  const int itend = it0 + itn;
  __shared__ u16 sA[64 * SAS];                        // 9216 B
  __shared__ u16 sB[64 * SAS];                        // 9216 B
  const int t = threadIdx.x;
  const int w = t >> 6, L = t & 63;
  const int l16 = L & 15, q8 = (L >> 4) * 8;
  const int wm = (w >> 1) * 32, wn = (w & 1) * 32;    // 2x2 wave grid
  const int row = t >> 2, lk = t & 3;                 // A0/Wn staging coords
  const int pp = t >> 5, pg = t & 31;                 // Pf staging coords
  f32x4 acc[2][2] = {{{0.f,0.f,0.f,0.f},{0.f,0.f,0.f,0.f}},
                     {{0.f,0.f,0.f,0.f},{0.f,0.f,0.f,0.f}}};
  u16x8 raA[2], rbA[2], raB[2], rbB[2];               // two named slot sets

#define LOAD_T(IT, RA, RB)                                                    \
  {                                                                           \
    const int k0_ = (IT) * 64;                                                \
    if (k0_ < 896) {                                                          \
      const u16* s_ = A0 + (size_t)(bm0 + row) * 896 + k0_ + lk * 8;          \
      RA[0] = *(const u16x8*)(s_);                                            \
      RA[1] = *(const u16x8*)(s_ + 32);                                       \
    } else {                                                                  \
      const int fb_ = (k0_ - 896) >> 3;                                       \
      const u16* s_ = Pf + ((size_t)(fb_ + pp) * B_ + bm0 + pg) * 8;          \
      RA[0] = *(const u16x8*)(s_);                                            \
      RA[1] = *(const u16x8*)(s_ + 256);   /* +32 rows */                     \
    }                                                                         \
    const u16* sb_ = Wn + (size_t)(bn0 + row) * ZK + k0_ + lk * 8;            \
    RB[0] = *(const u16x8*)(sb_);                                             \
    RB[1] = *(const u16x8*)(sb_ + 32);                                        \
  }

#define STORE_T(IT, RA, RB)                                                   \
  {                                                                           \
    if ((IT) * 64 < 896) {                                                    \
      *(u16x8*)&sA[row * SAS + lk * 8]      = RA[0];                          \
      *(u16x8*)&sA[row * SAS + lk * 8 + 32] = RA[1];                          \
    } else {                                                                  \
      *(u16x8*)&sA[pg * SAS + pp * 8]        = RA[0];                         \
      *(u16x8*)&sA[(pg + 32) * SAS + pp * 8] = RA[1];                         \
    }                                                                         \
    *(u16x8*)&sB[row * SAS + lk * 8]      = RB[0];                            \
    *(u16x8*)&sB[row * SAS + lk * 8 + 32] = RB[1];                            \
  }

#define MFMA_BLOCK()                                                          \
  {                                                                           \
    _Pragma("unroll")                                                         \
    for (int ks = 0; ks < 2; ++ks) {                                          \
      s16x8 a0 = *(const s16x8*)&sA[(wm + l16) * SAS + ks * 32 + q8];         \
      s16x8 a1 = *(const s16x8*)&sA[(wm + 16 + l16) * SAS + ks * 32 + q8];    \
      s16x8 b0 = *(const s16x8*)&sB[(wn + l16) * SAS + ks * 32 + q8];         \
      s16x8 b1 = *(const s16x8*)&sB[(wn + 16 + l16) * SAS + ks * 32 + q8];    \
      acc[0][0] = __builtin_amdgcn_mfma_f32_16x16x32_bf16(a0, b0, acc[0][0], 0, 0, 0); \
      acc[0][1] = __builtin_amdgcn_mfma_f32_16x16x32_bf16(a0, b1, acc[0][1], 0, 0, 0); \
      acc[1][0] = __builtin_amdgcn_mfma_f32_16x16x32_bf16(a1, b0, acc[1][0], 0, 0, 0); \
      acc[1][1] = __builtin_amdgcn_mfma_f32_16x16x32_bf16(a1, b1, acc[1][1], 0, 0, 0); \
    }                                                                         \
  }

  LOAD_T(it0, raA, rbA);
  LOAD_T(it0 + 1, raB, rbB);                          // itn >= 8 always
  for (int itp = it0; itp < itend; itp += 2) {
    // ---- tile itp (slot A) ----
    __syncthreads();
    STORE_T(itp, raA, rbA);
    __syncthreads();
    if (itp + 2 < itend) LOAD_T(itp + 2, raA, rbA);   // distance-2 prefetch
    MFMA_BLOCK();
    // ---- tile itp+1 (slot B) ----
    __syncthreads();
    STORE_T(itp + 1, raB, rbB);
    __syncthreads();
    if (itp + 3 < itend) LOAD_T(itp + 3, raB, rbB);   // distance-2 prefetch
    MFMA_BLOCK();
  }
#undef LOAD_T
#undef STORE_T
#undef MFMA_BLOCK

  float* dst = part + (size_t)kz * B_ * OUT_;
  #pragma unroll
  for (int mf = 0; mf < 2; ++mf) {
    const int r0 = bm0 + wm + mf * 16 + (L >> 4) * 4;   // C/D: col=lane&15, row=quad*4+i
    #pragma unroll
    for (int nf = 0; nf < 2; ++nf) {
      const int col = bn0 + wn + nf * 16 + l16;
      #pragma unroll
      for (int i = 0; i < 4; ++i)
        dst[(size_t)(r0 + i) * OUT_ + col] = acc[mf][nf][i];
    }
  }
}

// ---------------------------------------------------------------------------
// combine: out = relu(sum_kz part[kz] + bias), float4 per thread
__global__ __launch_bounds__(256) void combine_kernel(
    const float* __restrict__ part, const float* __restrict__ pb,
    float* __restrict__ out) {
  const int idx4 = (blockIdx.x * 256 + threadIdx.x) * 4;
  const int o = idx4 & (OUT_ - 1);
  float4 bv = *(const float4*)(pb + o);
  float4 r = bv;
  #pragma unroll
  for (int kz = 0; kz < NSPLIT; ++kz) {
    float4 a = *(const float4*)(part + (size_t)kz * B_ * OUT_ + idx4);
    r.x += a.x; r.y += a.y; r.z += a.z; r.w += a.w;
  }
  r.x = r.x > 0.f ? r.x : 0.f;
  r.y = r.y > 0.f ? r.y : 0.f;
  r.z = r.z > 0.f ? r.z : 0.f;
  r.w = r.w > 0.f ? r.w : 0.f;
  *(float4*)(out + idx4) = r;
}

// ---------------------------------------------------------------------------
extern "C" void kernel_launch(void* const* d_in, const int* in_sizes, int n_in,
                              void* d_out, int out_size, void* d_ws, size_t ws_size,
                              hipStream_t stream) {
  (void)in_sizes; (void)n_in; (void)out_size; (void)ws_size;
  const float* stat = (const float*)d_in[0];
  const float* asr  = (const float*)d_in[1];
  const float* mm   = (const float*)d_in[2];
  const float* w1   = (const float*)d_in[3];
  const float* b1   = (const float*)d_in[4];
  const float* w2   = (const float*)d_in[5];
  const float* b2   = (const float*)d_in[6];
  const float* tau  = (const float*)d_in[7];
  const float* emb  = (const float*)d_in[8];
  const float* pw   = (const float*)d_in[9];
  const float* pb   = (const float*)d_in[10];
  float* out = (float*)d_out;
  char* ws = (char*)d_ws;
  u16*   A0   = (u16*)(ws);                 //  3,670,016 B
  u16*   Pf   = (u16*)(ws + 3670016);       // 16,777,216 B
  u16*   Wn   = (u16*)(ws + 20447232);      //  2,555,904 B
  float* part = (float*)(ws + 23003136);    // 16,777,216 B (NSPLIT=8)

  producer_kernel<<<PRODUCER_BLOCKS, 256, 0, stream>>>(
      stat, w1, b1, w2, b2, tau, pw, emb, asr, mm, A0, Pf, Wn);
  gemm_kernel<<<dim3(B_ / 64, OUT_ / 64, NSPLIT), 256, 0, stream>>>(
      A0, Pf, Wn, part);
  combine_kernel<<<B_ * OUT_ / 1024, 256, 0, stream>>>(part, pb, out);
}